// Round 4
// baseline (1904.636 us; speedup 1.0000x reference)
//
#include <hip/hip_runtime.h>
#include <math.h>

#define N_NODES 100000
#define N_EDGES 3200000
#define H 32
#define SCAN_BLOCKS ((N_NODES + 255) / 256)   // 391

__device__ __forceinline__ float lrelu(float v) { return v > 0.0f ? v : 0.01f * v; }

// out = bias + in @ W   (W is [H,H] row-major: W[k*H+o]); uniform W/bias -> s_loads
__device__ __forceinline__ void matvec32(const float* __restrict__ in,
                                         const float* __restrict__ W,
                                         const float* __restrict__ bias,
                                         float* __restrict__ out) {
#pragma unroll
    for (int o = 0; o < H; ++o) out[o] = bias[o];
#pragma unroll
    for (int k = 0; k < H; ++k) {
        float v = in[k];
#pragma unroll
        for (int o = 0; o < H; ++o) out[o] = fmaf(v, W[k * H + o], out[o]);
    }
}

// out += in @ W
__device__ __forceinline__ void matvec32_acc(const float* __restrict__ in,
                                             const float* __restrict__ W,
                                             float* __restrict__ out) {
#pragma unroll
    for (int k = 0; k < H; ++k) {
        float v = in[k];
#pragma unroll
        for (int o = 0; o < H; ++o) out[o] = fmaf(v, W[k * H + o], out[o]);
    }
}

__device__ __forceinline__ void load_row32(const float* __restrict__ p, float* __restrict__ r) {
    const float4* p4 = reinterpret_cast<const float4*>(p);
#pragma unroll
    for (int q = 0; q < 8; ++q) {
        float4 v = p4[q];
        r[4 * q + 0] = v.x; r[4 * q + 1] = v.y; r[4 * q + 2] = v.z; r[4 * q + 3] = v.w;
    }
}

__device__ __forceinline__ void store_row32(float* __restrict__ p, const float* __restrict__ r) {
    float4* p4 = reinterpret_cast<float4*>(p);
#pragma unroll
    for (int q = 0; q < 8; ++q) {
        float4 v;
        v.x = r[4 * q + 0]; v.y = r[4 * q + 1]; v.z = r[4 * q + 2]; v.w = r[4 * q + 3];
        p4[q] = v;
    }
}

// h_node row for node i from x[i] (W_in is [3,H])
__device__ __forceinline__ void hnode_row(const float* __restrict__ x, int i,
                                          const float* __restrict__ W_in,
                                          const float* __restrict__ b_in,
                                          float* __restrict__ r) {
    float x0 = x[(size_t)i * 3 + 0], x1 = x[(size_t)i * 3 + 1], x2 = x[(size_t)i * 3 + 2];
#pragma unroll
    for (int o = 0; o < H; ++o)
        r[o] = fmaf(x2, W_in[2 * H + o], fmaf(x1, W_in[1 * H + o], fmaf(x0, W_in[0 * H + o], b_in[o])));
}

// ---------------- CSR build ----------------
__global__ __launch_bounds__(256) void zero_int_kernel(int* __restrict__ p, int n) {
    int i = blockIdx.x * blockDim.x + threadIdx.x;
    if (i < n) p[i] = 0;
}

__global__ __launch_bounds__(256) void hist_kernel(const int* __restrict__ eidx, int* __restrict__ cnt) {
    int e = blockIdx.x * blockDim.x + threadIdx.x;
    if (e >= N_EDGES) return;
    atomicAdd(&cnt[eidx[(size_t)N_EDGES + e]], 1);
}

// per-block exclusive scan of cnt -> ptr (block-local), block totals -> bsum
__global__ __launch_bounds__(256) void scan_block_kernel(const int* __restrict__ cnt,
                                                         int* __restrict__ ptr,
                                                         int* __restrict__ bsum) {
    __shared__ int sm[256];
    int idx = blockIdx.x * 256 + threadIdx.x;
    int v = (idx < N_NODES) ? cnt[idx] : 0;
    sm[threadIdx.x] = v;
    __syncthreads();
    for (int off = 1; off < 256; off <<= 1) {
        int t = (threadIdx.x >= off) ? sm[threadIdx.x - off] : 0;
        __syncthreads();
        sm[threadIdx.x] += t;
        __syncthreads();
    }
    if (idx < N_NODES) ptr[idx] = sm[threadIdx.x] - v;   // exclusive within block
    if (threadIdx.x == 255) bsum[blockIdx.x] = sm[255];
}

// single-block exclusive scan of bsum[0..nb)
__global__ __launch_bounds__(512) void scan_bsum_kernel(int* __restrict__ bsum, int nb) {
    __shared__ int sm[512];
    int v = (threadIdx.x < nb) ? bsum[threadIdx.x] : 0;
    sm[threadIdx.x] = v;
    __syncthreads();
    for (int off = 1; off < 512; off <<= 1) {
        int t = (threadIdx.x >= off) ? sm[threadIdx.x - off] : 0;
        __syncthreads();
        sm[threadIdx.x] += t;
        __syncthreads();
    }
    if (threadIdx.x < nb) bsum[threadIdx.x] = sm[threadIdx.x] - v;  // exclusive
}

// add block offsets; init fill = ptr; set ptr[N]
__global__ __launch_bounds__(256) void scan_fix_kernel(int* __restrict__ ptr,
                                                       int* __restrict__ fill,
                                                       const int* __restrict__ bsum) {
    int idx = blockIdx.x * 256 + threadIdx.x;
    if (idx < N_NODES) {
        int p = ptr[idx] + bsum[blockIdx.x];
        ptr[idx] = p;
        fill[idx] = p;
    }
    if (idx == 0) ptr[N_NODES] = N_EDGES;
}

__global__ __launch_bounds__(256) void scatter_kernel(const int* __restrict__ eidx,
                                                      int* __restrict__ fill,
                                                      int* __restrict__ sorted) {
    int e = blockIdx.x * blockDim.x + threadIdx.x;
    if (e >= N_EDGES) return;
    int dst = eidx[(size_t)N_EDGES + e];
    int pos = atomicAdd(&fill[dst], 1);
    sorted[pos] = e;
}

// ---------------- CSR gather-reduce ----------------
// out[n][c] = sum over incoming edges of rows[eid][c]; if TRANSFORM, then
// out[n] = (sum rows) @ W + cnt_n * bias   (linearity of the encoder)
template <bool TRANSFORM>
__global__ __launch_bounds__(256) void aggr_kernel(const float* __restrict__ rows,
                                                   const int* __restrict__ ptr,
                                                   const int* __restrict__ sorted,
                                                   const float* __restrict__ W,
                                                   const float* __restrict__ bias,
                                                   float* __restrict__ out) {
    __shared__ float sm[256];
    int t = blockIdx.x * blockDim.x + threadIdx.x;   // grid exactly N_NODES*H threads
    int n = t >> 5, c = t & 31;
    int b = ptr[n], e = ptr[n + 1];
    float acc = 0.0f;
    for (int i = b; i < e; ++i) acc += rows[(size_t)sorted[i] * H + c];
    if (!TRANSFORM) {
        out[(size_t)n * H + c] = acc;
        return;
    }
    sm[threadIdx.x] = acc;
    __syncthreads();
    const float* s = sm + (threadIdx.x & ~31);       // this node's 32 summed channels
    float r = (float)(e - b) * bias[c];
#pragma unroll
    for (int k = 0; k < H; ++k) r = fmaf(s[k], W[k * H + c], r);
    out[(size_t)n * H + c] = r;
}

// ---------------- pass2: per-edge message + outputs (no atomics) ----------------
__global__ __launch_bounds__(256) void edge_pass2_kernel(
    const float* __restrict__ h_msg, const int* __restrict__ eidx,
    const float* __restrict__ x, const float* __restrict__ aggr_msgs,
    const float* __restrict__ W_in, const float* __restrict__ b_in,
    const float* __restrict__ We, const float* __restrict__ be,
    const float* __restrict__ Wn1, const float* __restrict__ bn1,
    const float* __restrict__ Wn2, const float* __restrict__ bn2,
    const float* __restrict__ WN1, const float* __restrict__ bN1,
    const float* __restrict__ WN2, const float* __restrict__ bN2,
    const float* __restrict__ Wd, const float* __restrict__ bd,
    float* __restrict__ out_hmsg, float* __restrict__ out_ymsg) {
    int e = blockIdx.x * blockDim.x + threadIdx.x;
    if (e >= N_EDGES) return;

    int src = eidx[e];

    float buf0[H], buf1[H], enc[H], nn[H];

    // encoded = h_msg[e] @ We + be (recomputed; cheaper than a 2nd 410MB stream)
    load_row32(h_msg + (size_t)e * H, buf0);
    matvec32(buf0, We, be, enc);

    // nn = lrelu(lrelu(h_node[src] @ Wn1 + bn1) @ Wn2 + bn2); h_node recomputed from x
    hnode_row(x, src, W_in, b_in, buf0);
    matvec32(buf0, Wn1, bn1, buf1);
#pragma unroll
    for (int o = 0; o < H; ++o) buf1[o] = lrelu(buf1[o]);
    matvec32(buf1, Wn2, bn2, nn);
#pragma unroll
    for (int o = 0; o < H; ++o) nn[o] = lrelu(nn[o]);

    // n_out = lrelu(lrelu([aggr_msgs[src], enc] @ WN1 + bN1) @ WN2 + bN2)
    load_row32(aggr_msgs + (size_t)src * H, buf0);
    matvec32(buf0, WN1, bN1, buf1);          // top half of WN1
    matvec32_acc(enc, WN1 + H * H, buf1);    // bottom half of WN1
#pragma unroll
    for (int o = 0; o < H; ++o) buf1[o] = lrelu(buf1[o]);
    matvec32(buf1, WN2, bN2, buf0);
#pragma unroll
    for (int o = 0; o < H; ++o) nn[o] += lrelu(buf0[o]);   // h_msg_new

    store_row32(out_hmsg + (size_t)e * H, nn);

    // y_msg = softmax(h_msg_new @ Wd + bd)
    float z0 = bd[0], z1 = bd[1];
#pragma unroll
    for (int k = 0; k < H; ++k) {
        z0 = fmaf(nn[k], Wd[k * 2 + 0], z0);
        z1 = fmaf(nn[k], Wd[k * 2 + 1], z1);
    }
    float zm = fmaxf(z0, z1);
    float e0 = __expf(z0 - zm), e1 = __expf(z1 - zm);
    float inv = 1.0f / (e0 + e1);
    out_ymsg[(size_t)e * 2 + 0] = e0 * inv;
    out_ymsg[(size_t)e * 2 + 1] = e1 * inv;
}

// ---------------- node update + beliefs ----------------
__global__ __launch_bounds__(256) void node_update_kernel(
    const float* __restrict__ x, const float* __restrict__ aggr_out,
    const float* __restrict__ W_in, const float* __restrict__ b_in,
    const float* __restrict__ WU, const float* __restrict__ bU,
    const float* __restrict__ Wb, const float* __restrict__ bb,
    float* __restrict__ out_beliefs) {
    int i = blockIdx.x * blockDim.x + threadIdx.x;
    if (i >= N_NODES) return;
    float a[H], t[H];
    hnode_row(x, i, W_in, b_in, a);
    matvec32(a, WU, bU, t);
    load_row32(aggr_out + (size_t)i * H, a);
    matvec32_acc(a, WU + H * H, t);
#pragma unroll
    for (int o = 0; o < H; ++o) t[o] = lrelu(t[o]);

    // beliefs only for variable nodes (x[:,0]==1, contiguous prefix -> out row == i)
    if (x[(size_t)i * 3] == 1.0f) {
        float z0 = bb[0], z1 = bb[1];
#pragma unroll
        for (int k = 0; k < H; ++k) {
            z0 = fmaf(t[k], Wb[k * 2 + 0], z0);
            z1 = fmaf(t[k], Wb[k * 2 + 1], z1);
        }
        float zm = fmaxf(z0, z1);
        float e0 = __expf(z0 - zm), e1 = __expf(z1 - zm);
        float inv = 1.0f / (e0 + e1);
        out_beliefs[(size_t)i * 2 + 0] = e0 * inv;
        out_beliefs[(size_t)i * 2 + 1] = e1 * inv;
    }
}

extern "C" void kernel_launch(void* const* d_in, const int* in_sizes, int n_in,
                              void* d_out, int out_size, void* d_ws, size_t ws_size,
                              hipStream_t stream) {
    const float* x     = (const float*)d_in[0];
    const int*   eidx  = (const int*)d_in[1];
    const float* h_msg = (const float*)d_in[2];
    const float* W_in = (const float*)d_in[3];  const float* b_in = (const float*)d_in[4];
    const float* We   = (const float*)d_in[5];  const float* be   = (const float*)d_in[6];
    const float* Wn1  = (const float*)d_in[7];  const float* bn1  = (const float*)d_in[8];
    const float* Wn2  = (const float*)d_in[9];  const float* bn2  = (const float*)d_in[10];
    const float* WN1  = (const float*)d_in[11]; const float* bN1  = (const float*)d_in[12];
    const float* WN2  = (const float*)d_in[13]; const float* bN2  = (const float*)d_in[14];
    const float* WU   = (const float*)d_in[15]; const float* bU   = (const float*)d_in[16];
    const float* Wd   = (const float*)d_in[17]; const float* bd   = (const float*)d_in[18];
    const float* Wb   = (const float*)d_in[19]; const float* bb   = (const float*)d_in[20];

    float* out         = (float*)d_out;
    float* out_hmsg    = out;
    float* out_ymsg    = out + (size_t)N_EDGES * H;
    float* out_beliefs = out + (size_t)N_EDGES * (H + 2);

    // workspace layout
    float* aggr_msgs = (float*)d_ws;                           // [N, H]
    float* aggr_out  = aggr_msgs + (size_t)N_NODES * H;        // [N, H]
    int*   cnt       = (int*)(aggr_out + (size_t)N_NODES * H); // [N]
    int*   ptr       = cnt + N_NODES;                          // [N+1]
    int*   fill      = ptr + (N_NODES + 1);                    // [N]
    int*   bsum      = fill + N_NODES;                         // [512]
    int*   sorted    = bsum + 512;                             // [E]

    const int EB   = (N_EDGES + 255) / 256;       // 12500
    const int NB32 = (N_NODES * H) / 256;         // 12500 (exact)

    // --- CSR build (by dst) ---
    zero_int_kernel<<<SCAN_BLOCKS, 256, 0, stream>>>(cnt, N_NODES);
    hist_kernel<<<EB, 256, 0, stream>>>(eidx, cnt);
    scan_block_kernel<<<SCAN_BLOCKS, 256, 0, stream>>>(cnt, ptr, bsum);
    scan_bsum_kernel<<<1, 512, 0, stream>>>(bsum, SCAN_BLOCKS);
    scan_fix_kernel<<<SCAN_BLOCKS, 256, 0, stream>>>(ptr, fill, bsum);
    scatter_kernel<<<EB, 256, 0, stream>>>(eidx, fill, sorted);

    // --- aggr_msgs = segment_sum(h_msg)@We + cnt*be  (encoder linearity) ---
    aggr_kernel<true><<<NB32, 256, 0, stream>>>(h_msg, ptr, sorted, We, be, aggr_msgs);

    // --- per-edge messages ---
    edge_pass2_kernel<<<EB, 256, 0, stream>>>(
        h_msg, eidx, x, aggr_msgs,
        W_in, b_in, We, be, Wn1, bn1, Wn2, bn2, WN1, bN1, WN2, bN2, Wd, bd,
        out_hmsg, out_ymsg);

    // --- aggr_out = segment_sum(h_msg_new, dst) ---
    aggr_kernel<false><<<NB32, 256, 0, stream>>>(out_hmsg, ptr, sorted, nullptr, nullptr, aggr_out);

    // --- node update + beliefs ---
    node_update_kernel<<<SCAN_BLOCKS, 256, 0, stream>>>(
        x, aggr_out, W_in, b_in, WU, bU, Wb, bb, out_beliefs);
}

// Round 5
// 1410.406 us; speedup vs baseline: 1.3504x; 1.3504x over previous
//
#include <hip/hip_runtime.h>
#include <math.h>

#define N_NODES 100000
#define N_EDGES 3200000
#define H 32
#define SCAN_BLOCKS ((N_NODES + 255) / 256)   // 391

__device__ __forceinline__ float lrelu(float v) { return v > 0.0f ? v : 0.01f * v; }

// out = bias + in @ W   (W is [H,H] row-major: W[k*H+o]); uniform W/bias -> s_loads
__device__ __forceinline__ void matvec32(const float* __restrict__ in,
                                         const float* __restrict__ W,
                                         const float* __restrict__ bias,
                                         float* __restrict__ out) {
#pragma unroll
    for (int o = 0; o < H; ++o) out[o] = bias[o];
#pragma unroll
    for (int k = 0; k < H; ++k) {
        float v = in[k];
#pragma unroll
        for (int o = 0; o < H; ++o) out[o] = fmaf(v, W[k * H + o], out[o]);
    }
}

// out += in @ W
__device__ __forceinline__ void matvec32_acc(const float* __restrict__ in,
                                             const float* __restrict__ W,
                                             float* __restrict__ out) {
#pragma unroll
    for (int k = 0; k < H; ++k) {
        float v = in[k];
#pragma unroll
        for (int o = 0; o < H; ++o) out[o] = fmaf(v, W[k * H + o], out[o]);
    }
}

__device__ __forceinline__ void load_row32(const float* __restrict__ p, float* __restrict__ r) {
    const float4* p4 = reinterpret_cast<const float4*>(p);
#pragma unroll
    for (int q = 0; q < 8; ++q) {
        float4 v = p4[q];
        r[4 * q + 0] = v.x; r[4 * q + 1] = v.y; r[4 * q + 2] = v.z; r[4 * q + 3] = v.w;
    }
}

__device__ __forceinline__ void store_row32(float* __restrict__ p, const float* __restrict__ r) {
    float4* p4 = reinterpret_cast<float4*>(p);
#pragma unroll
    for (int q = 0; q < 8; ++q) {
        float4 v;
        v.x = r[4 * q + 0]; v.y = r[4 * q + 1]; v.z = r[4 * q + 2]; v.w = r[4 * q + 3];
        p4[q] = v;
    }
}

// h_node row for node i from x[i] (W_in is [3,H])
__device__ __forceinline__ void hnode_row(const float* __restrict__ x, int i,
                                          const float* __restrict__ W_in,
                                          const float* __restrict__ b_in,
                                          float* __restrict__ r) {
    float x0 = x[(size_t)i * 3 + 0], x1 = x[(size_t)i * 3 + 1], x2 = x[(size_t)i * 3 + 2];
#pragma unroll
    for (int o = 0; o < H; ++o)
        r[o] = fmaf(x2, W_in[2 * H + o], fmaf(x1, W_in[1 * H + o], fmaf(x0, W_in[0 * H + o], b_in[o])));
}

// ---------------- fold: W2 = We@WN1top, Wfold = We@WN1bot, c1 = be@WN1top,
//                  c0 = bN1 + be@WN1bot ----------------
__global__ __launch_bounds__(1024) void fold_kernel(const float* __restrict__ We,
                                                    const float* __restrict__ be,
                                                    const float* __restrict__ WN1,
                                                    const float* __restrict__ bN1,
                                                    float* __restrict__ W2,
                                                    float* __restrict__ Wfold,
                                                    float* __restrict__ c1,
                                                    float* __restrict__ c0) {
    int t = threadIdx.x;
    int k = t >> 5, o = t & 31;
    float s2 = 0.0f, sf = 0.0f;
#pragma unroll
    for (int j = 0; j < H; ++j) {
        float w = We[k * H + j];
        s2 = fmaf(w, WN1[j * H + o], s2);
        sf = fmaf(w, WN1[(H + j) * H + o], sf);
    }
    W2[t] = s2;
    Wfold[t] = sf;
    if (k == 0) {
        float a = 0.0f, b = 0.0f;
#pragma unroll
        for (int j = 0; j < H; ++j) {
            a = fmaf(be[j], WN1[j * H + o], a);
            b = fmaf(be[j], WN1[(H + j) * H + o], b);
        }
        c1[o] = a;
        c0[o] = bN1[o] + b;
    }
}

// ---------------- CSR build ----------------
__global__ __launch_bounds__(256) void zero_int_kernel(int* __restrict__ p, int n) {
    int i = blockIdx.x * blockDim.x + threadIdx.x;
    if (i < n) p[i] = 0;
}

__global__ __launch_bounds__(256) void hist_kernel(const int* __restrict__ eidx, int* __restrict__ cnt) {
    int e = blockIdx.x * blockDim.x + threadIdx.x;
    if (e >= N_EDGES) return;
    atomicAdd(&cnt[eidx[(size_t)N_EDGES + e]], 1);
}

__global__ __launch_bounds__(256) void scan_block_kernel(const int* __restrict__ cnt,
                                                         int* __restrict__ ptr,
                                                         int* __restrict__ bsum) {
    __shared__ int sm[256];
    int idx = blockIdx.x * 256 + threadIdx.x;
    int v = (idx < N_NODES) ? cnt[idx] : 0;
    sm[threadIdx.x] = v;
    __syncthreads();
    for (int off = 1; off < 256; off <<= 1) {
        int t = (threadIdx.x >= off) ? sm[threadIdx.x - off] : 0;
        __syncthreads();
        sm[threadIdx.x] += t;
        __syncthreads();
    }
    if (idx < N_NODES) ptr[idx] = sm[threadIdx.x] - v;   // exclusive within block
    if (threadIdx.x == 255) bsum[blockIdx.x] = sm[255];
}

__global__ __launch_bounds__(512) void scan_bsum_kernel(int* __restrict__ bsum, int nb) {
    __shared__ int sm[512];
    int v = (threadIdx.x < nb) ? bsum[threadIdx.x] : 0;
    sm[threadIdx.x] = v;
    __syncthreads();
    for (int off = 1; off < 512; off <<= 1) {
        int t = (threadIdx.x >= off) ? sm[threadIdx.x - off] : 0;
        __syncthreads();
        sm[threadIdx.x] += t;
        __syncthreads();
    }
    if (threadIdx.x < nb) bsum[threadIdx.x] = sm[threadIdx.x] - v;  // exclusive
}

__global__ __launch_bounds__(256) void scan_fix_kernel(int* __restrict__ ptr,
                                                       int* __restrict__ fill,
                                                       const int* __restrict__ bsum) {
    int idx = blockIdx.x * 256 + threadIdx.x;
    if (idx < N_NODES) {
        int p = ptr[idx] + bsum[blockIdx.x];
        ptr[idx] = p;
        fill[idx] = p;
    }
    if (idx == 0) ptr[N_NODES] = N_EDGES;
}

__global__ __launch_bounds__(256) void scatter_kernel(const int* __restrict__ eidx,
                                                      int* __restrict__ fill,
                                                      int* __restrict__ sorted) {
    int e = blockIdx.x * blockDim.x + threadIdx.x;
    if (e >= N_EDGES) return;
    int dst = eidx[(size_t)N_EDGES + e];
    int pos = atomicAdd(&fill[dst], 1);
    sorted[pos] = e;
}

// ---------------- aggr_pre1: pre1[n] = (sum h_msg)@W2 + cnt*c1 + c0 ----------------
__global__ __launch_bounds__(256) void aggr_pre1_kernel(const float* __restrict__ rows,
                                                        const int* __restrict__ ptr,
                                                        const int* __restrict__ sorted,
                                                        const float* __restrict__ W2,
                                                        const float* __restrict__ c1,
                                                        const float* __restrict__ c0,
                                                        float* __restrict__ pre1) {
    __shared__ float sm[256];
    int t = blockIdx.x * blockDim.x + threadIdx.x;   // grid exactly N_NODES*H threads
    int n = t >> 5, c = t & 31;
    int b = ptr[n], e = ptr[n + 1];
    float acc = 0.0f;
    for (int i = b; i < e; ++i) acc += rows[(size_t)sorted[i] * H + c];
    sm[threadIdx.x] = acc;
    __syncthreads();
    const float* s = sm + (threadIdx.x & ~31);
    float r = fmaf((float)(e - b), c1[c], c0[c]);
#pragma unroll
    for (int k = 0; k < H; ++k) r = fmaf(s[k], W2[k * H + c], r);
    pre1[(size_t)n * H + c] = r;
}

// ---------------- plain segment sum (for aggr_out) ----------------
__global__ __launch_bounds__(256) void aggr_sum_kernel(const float* __restrict__ rows,
                                                       const int* __restrict__ ptr,
                                                       const int* __restrict__ sorted,
                                                       float* __restrict__ out) {
    int t = blockIdx.x * blockDim.x + threadIdx.x;   // grid exactly N_NODES*H threads
    int n = t >> 5, c = t & 31;
    int b = ptr[n], e = ptr[n + 1];
    float acc = 0.0f;
    for (int i = b; i < e; ++i) acc += rows[(size_t)sorted[i] * H + c];
    out[(size_t)n * H + c] = acc;
}

// ---------------- nn_node: per-node N_node MLP ----------------
__global__ __launch_bounds__(256) void nn_node_kernel(const float* __restrict__ x,
                                                      const float* __restrict__ W_in,
                                                      const float* __restrict__ b_in,
                                                      const float* __restrict__ Wn1,
                                                      const float* __restrict__ bn1,
                                                      const float* __restrict__ Wn2,
                                                      const float* __restrict__ bn2,
                                                      float* __restrict__ nn_node) {
    int i = blockIdx.x * blockDim.x + threadIdx.x;
    if (i >= N_NODES) return;
    float a[H], b1[H], nn[H];
    hnode_row(x, i, W_in, b_in, a);
    matvec32(a, Wn1, bn1, b1);
#pragma unroll
    for (int o = 0; o < H; ++o) b1[o] = lrelu(b1[o]);
    matvec32(b1, Wn2, bn2, nn);
#pragma unroll
    for (int o = 0; o < H; ++o) nn[o] = lrelu(nn[o]);
    store_row32(nn_node + (size_t)i * H, nn);
}

// ---------------- pass2: per-edge, folded ----------------
__global__ __launch_bounds__(256) void edge_pass2_kernel(
    const float* __restrict__ h_msg, const int* __restrict__ eidx,
    const float* __restrict__ pre1, const float* __restrict__ nn_node,
    const float* __restrict__ Wfold,
    const float* __restrict__ WN2, const float* __restrict__ bN2,
    const float* __restrict__ Wd, const float* __restrict__ bd,
    float* __restrict__ out_hmsg, float* __restrict__ out_ymsg) {
    int e = blockIdx.x * blockDim.x + threadIdx.x;   // grid exact (3.2M/256)
    int src = eidx[e];

    float m[H], t[H], u[H];

    // t = pre1[src] + h_msg[e] @ Wfold     (== cat_e @ WN1 + bN1)
    load_row32(h_msg + (size_t)e * H, m);
    load_row32(pre1 + (size_t)src * H, t);
    matvec32_acc(m, Wfold, t);
#pragma unroll
    for (int o = 0; o < H; ++o) t[o] = lrelu(t[o]);

    // u = t @ WN2 + bN2
    matvec32(t, WN2, bN2, u);

    // h_msg_new = nn_node[src] + lrelu(u)
    load_row32(nn_node + (size_t)src * H, t);
#pragma unroll
    for (int o = 0; o < H; ++o) m[o] = t[o] + lrelu(u[o]);

    store_row32(out_hmsg + (size_t)e * H, m);

    // y_msg = softmax(h_msg_new @ Wd + bd)
    float z0 = bd[0], z1 = bd[1];
#pragma unroll
    for (int k = 0; k < H; ++k) {
        z0 = fmaf(m[k], Wd[k * 2 + 0], z0);
        z1 = fmaf(m[k], Wd[k * 2 + 1], z1);
    }
    float zm = fmaxf(z0, z1);
    float e0 = __expf(z0 - zm), e1 = __expf(z1 - zm);
    float inv = 1.0f / (e0 + e1);
    out_ymsg[(size_t)e * 2 + 0] = e0 * inv;
    out_ymsg[(size_t)e * 2 + 1] = e1 * inv;
}

// ---------------- node update + beliefs ----------------
__global__ __launch_bounds__(256) void node_update_kernel(
    const float* __restrict__ x, const float* __restrict__ aggr_out,
    const float* __restrict__ W_in, const float* __restrict__ b_in,
    const float* __restrict__ WU, const float* __restrict__ bU,
    const float* __restrict__ Wb, const float* __restrict__ bb,
    float* __restrict__ out_beliefs) {
    int i = blockIdx.x * blockDim.x + threadIdx.x;
    if (i >= N_NODES) return;
    float a[H], t[H];
    hnode_row(x, i, W_in, b_in, a);
    matvec32(a, WU, bU, t);
    load_row32(aggr_out + (size_t)i * H, a);
    matvec32_acc(a, WU + H * H, t);
#pragma unroll
    for (int o = 0; o < H; ++o) t[o] = lrelu(t[o]);

    // beliefs only for variable nodes (x[:,0]==1, contiguous prefix -> out row == i)
    if (x[(size_t)i * 3] == 1.0f) {
        float z0 = bb[0], z1 = bb[1];
#pragma unroll
        for (int k = 0; k < H; ++k) {
            z0 = fmaf(t[k], Wb[k * 2 + 0], z0);
            z1 = fmaf(t[k], Wb[k * 2 + 1], z1);
        }
        float zm = fmaxf(z0, z1);
        float e0 = __expf(z0 - zm), e1 = __expf(z1 - zm);
        float inv = 1.0f / (e0 + e1);
        out_beliefs[(size_t)i * 2 + 0] = e0 * inv;
        out_beliefs[(size_t)i * 2 + 1] = e1 * inv;
    }
}

extern "C" void kernel_launch(void* const* d_in, const int* in_sizes, int n_in,
                              void* d_out, int out_size, void* d_ws, size_t ws_size,
                              hipStream_t stream) {
    const float* x     = (const float*)d_in[0];
    const int*   eidx  = (const int*)d_in[1];
    const float* h_msg = (const float*)d_in[2];
    const float* W_in = (const float*)d_in[3];  const float* b_in = (const float*)d_in[4];
    const float* We   = (const float*)d_in[5];  const float* be   = (const float*)d_in[6];
    const float* Wn1  = (const float*)d_in[7];  const float* bn1  = (const float*)d_in[8];
    const float* Wn2  = (const float*)d_in[9];  const float* bn2  = (const float*)d_in[10];
    const float* WN1  = (const float*)d_in[11]; const float* bN1  = (const float*)d_in[12];
    const float* WN2  = (const float*)d_in[13]; const float* bN2  = (const float*)d_in[14];
    const float* WU   = (const float*)d_in[15]; const float* bU   = (const float*)d_in[16];
    const float* Wd   = (const float*)d_in[17]; const float* bd   = (const float*)d_in[18];
    const float* Wb   = (const float*)d_in[19]; const float* bb   = (const float*)d_in[20];

    float* out         = (float*)d_out;
    float* out_hmsg    = out;
    float* out_ymsg    = out + (size_t)N_EDGES * H;
    float* out_beliefs = out + (size_t)N_EDGES * (H + 2);

    // workspace layout (~40 MB)
    float* pre1    = (float*)d_ws;                              // [N, H]
    float* nnaggr  = pre1 + (size_t)N_NODES * H;                // [N, H] nn_node, then aggr_out
    float* W2      = nnaggr + (size_t)N_NODES * H;              // [H*H]
    float* Wfold   = W2 + H * H;                                // [H*H]
    float* c1      = Wfold + H * H;                             // [H]
    float* c0      = c1 + H;                                    // [H]
    int*   cnt     = (int*)(c0 + H);                            // [N]
    int*   ptr     = cnt + N_NODES;                             // [N+1]
    int*   fill    = ptr + (N_NODES + 1);                       // [N]
    int*   bsum    = fill + N_NODES;                            // [512]
    int*   sorted  = bsum + 512;                                // [E]

    const int EB   = N_EDGES / 256;          // 12500 exact
    const int NB32 = (N_NODES * H) / 256;    // 12500 exact

    // --- folded weight matrices ---
    fold_kernel<<<1, 1024, 0, stream>>>(We, be, WN1, bN1, W2, Wfold, c1, c0);

    // --- CSR build (by dst) ---
    zero_int_kernel<<<SCAN_BLOCKS, 256, 0, stream>>>(cnt, N_NODES);
    hist_kernel<<<EB, 256, 0, stream>>>(eidx, cnt);
    scan_block_kernel<<<SCAN_BLOCKS, 256, 0, stream>>>(cnt, ptr, bsum);
    scan_bsum_kernel<<<1, 512, 0, stream>>>(bsum, SCAN_BLOCKS);
    scan_fix_kernel<<<SCAN_BLOCKS, 256, 0, stream>>>(ptr, fill, bsum);
    scatter_kernel<<<EB, 256, 0, stream>>>(eidx, fill, sorted);

    // --- per-node precomputes ---
    nn_node_kernel<<<SCAN_BLOCKS, 256, 0, stream>>>(x, W_in, b_in, Wn1, bn1, Wn2, bn2, nnaggr);
    aggr_pre1_kernel<<<NB32, 256, 0, stream>>>(h_msg, ptr, sorted, W2, c1, c0, pre1);

    // --- per-edge messages ---
    edge_pass2_kernel<<<EB, 256, 0, stream>>>(
        h_msg, eidx, pre1, nnaggr, Wfold, WN2, bN2, Wd, bd, out_hmsg, out_ymsg);

    // --- aggr_out = segment_sum(h_msg_new, dst)  (reuses nnaggr slot) ---
    aggr_sum_kernel<<<NB32, 256, 0, stream>>>(out_hmsg, ptr, sorted, nnaggr);

    // --- node update + beliefs ---
    node_update_kernel<<<SCAN_BLOCKS, 256, 0, stream>>>(
        x, nnaggr, W_in, b_in, WU, bU, Wb, bb, out_beliefs);
}

// Round 6
// 1256.095 us; speedup vs baseline: 1.5163x; 1.1228x over previous
//
#include <hip/hip_runtime.h>
#include <math.h>

#define N_NODES 100000
#define N_EDGES 3200000
#define H 32
#define SCAN_BLOCKS ((N_NODES + 255) / 256)   // 391
#define SPG 128                               // slots per 32-lane group in seg_sum

__device__ __forceinline__ float lrelu(float v) { return v > 0.0f ? v : 0.01f * v; }

// out = bias + in @ W   (W is [H,H] row-major: W[k*H+o]); uniform W/bias -> s_loads
__device__ __forceinline__ void matvec32(const float* __restrict__ in,
                                         const float* __restrict__ W,
                                         const float* __restrict__ bias,
                                         float* __restrict__ out) {
#pragma unroll
    for (int o = 0; o < H; ++o) out[o] = bias[o];
#pragma unroll
    for (int k = 0; k < H; ++k) {
        float v = in[k];
#pragma unroll
        for (int o = 0; o < H; ++o) out[o] = fmaf(v, W[k * H + o], out[o]);
    }
}

// out += in @ W
__device__ __forceinline__ void matvec32_acc(const float* __restrict__ in,
                                             const float* __restrict__ W,
                                             float* __restrict__ out) {
#pragma unroll
    for (int k = 0; k < H; ++k) {
        float v = in[k];
#pragma unroll
        for (int o = 0; o < H; ++o) out[o] = fmaf(v, W[k * H + o], out[o]);
    }
}

__device__ __forceinline__ void load_row32(const float* __restrict__ p, float* __restrict__ r) {
    const float4* p4 = reinterpret_cast<const float4*>(p);
#pragma unroll
    for (int q = 0; q < 8; ++q) {
        float4 v = p4[q];
        r[4 * q + 0] = v.x; r[4 * q + 1] = v.y; r[4 * q + 2] = v.z; r[4 * q + 3] = v.w;
    }
}

__device__ __forceinline__ void store_row32(float* __restrict__ p, const float* __restrict__ r) {
    float4* p4 = reinterpret_cast<float4*>(p);
#pragma unroll
    for (int q = 0; q < 8; ++q) {
        float4 v;
        v.x = r[4 * q + 0]; v.y = r[4 * q + 1]; v.z = r[4 * q + 2]; v.w = r[4 * q + 3];
        p4[q] = v;
    }
}

// h_node row for node i from x[i] (W_in is [3,H])
__device__ __forceinline__ void hnode_row(const float* __restrict__ x, int i,
                                          const float* __restrict__ W_in,
                                          const float* __restrict__ b_in,
                                          float* __restrict__ r) {
    float x0 = x[(size_t)i * 3 + 0], x1 = x[(size_t)i * 3 + 1], x2 = x[(size_t)i * 3 + 2];
#pragma unroll
    for (int o = 0; o < H; ++o)
        r[o] = fmaf(x2, W_in[2 * H + o], fmaf(x1, W_in[1 * H + o], fmaf(x0, W_in[0 * H + o], b_in[o])));
}

// ---------------- fold: W2 = We@WN1top, Wfold = We@WN1bot, c1 = be@WN1top,
//                  c0 = bN1 + be@WN1bot ----------------
__global__ __launch_bounds__(1024) void fold_kernel(const float* __restrict__ We,
                                                    const float* __restrict__ be,
                                                    const float* __restrict__ WN1,
                                                    const float* __restrict__ bN1,
                                                    float* __restrict__ W2,
                                                    float* __restrict__ Wfold,
                                                    float* __restrict__ c1,
                                                    float* __restrict__ c0) {
    int t = threadIdx.x;
    int k = t >> 5, o = t & 31;
    float s2 = 0.0f, sf = 0.0f;
#pragma unroll
    for (int j = 0; j < H; ++j) {
        float w = We[k * H + j];
        s2 = fmaf(w, WN1[j * H + o], s2);
        sf = fmaf(w, WN1[(H + j) * H + o], sf);
    }
    W2[t] = s2;
    Wfold[t] = sf;
    if (k == 0) {
        float a = 0.0f, b = 0.0f;
#pragma unroll
        for (int j = 0; j < H; ++j) {
            a = fmaf(be[j], WN1[j * H + o], a);
            b = fmaf(be[j], WN1[(H + j) * H + o], b);
        }
        c1[o] = a;
        c0[o] = bN1[o] + b;
    }
}

// ---------------- utility zero kernels ----------------
__global__ __launch_bounds__(256) void zero_int_kernel(int* __restrict__ p, int n) {
    int i = blockIdx.x * blockDim.x + threadIdx.x;
    if (i < n) p[i] = 0;
}

__global__ __launch_bounds__(256) void zero_f4_kernel(float4* __restrict__ p, int n4) {
    int i = blockIdx.x * blockDim.x + threadIdx.x;
    if (i < n4) p[i] = make_float4(0.f, 0.f, 0.f, 0.f);
}

// ---------------- CSR build ----------------
__global__ __launch_bounds__(256) void hist_kernel(const int* __restrict__ eidx, int* __restrict__ cnt) {
    int e = blockIdx.x * blockDim.x + threadIdx.x;
    if (e >= N_EDGES) return;
    atomicAdd(&cnt[eidx[(size_t)N_EDGES + e]], 1);
}

__global__ __launch_bounds__(256) void scan_block_kernel(const int* __restrict__ cnt,
                                                         int* __restrict__ ptr,
                                                         int* __restrict__ bsum) {
    __shared__ int sm[256];
    int idx = blockIdx.x * 256 + threadIdx.x;
    int v = (idx < N_NODES) ? cnt[idx] : 0;
    sm[threadIdx.x] = v;
    __syncthreads();
    for (int off = 1; off < 256; off <<= 1) {
        int t = (threadIdx.x >= off) ? sm[threadIdx.x - off] : 0;
        __syncthreads();
        sm[threadIdx.x] += t;
        __syncthreads();
    }
    if (idx < N_NODES) ptr[idx] = sm[threadIdx.x] - v;   // exclusive within block
    if (threadIdx.x == 255) bsum[blockIdx.x] = sm[255];
}

__global__ __launch_bounds__(512) void scan_bsum_kernel(int* __restrict__ bsum, int nb) {
    __shared__ int sm[512];
    int v = (threadIdx.x < nb) ? bsum[threadIdx.x] : 0;
    sm[threadIdx.x] = v;
    __syncthreads();
    for (int off = 1; off < 512; off <<= 1) {
        int t = (threadIdx.x >= off) ? sm[threadIdx.x - off] : 0;
        __syncthreads();
        sm[threadIdx.x] += t;
        __syncthreads();
    }
    if (threadIdx.x < nb) bsum[threadIdx.x] = sm[threadIdx.x] - v;  // exclusive
}

__global__ __launch_bounds__(256) void scan_fix_kernel(int* __restrict__ ptr,
                                                       int* __restrict__ fill,
                                                       const int* __restrict__ bsum) {
    int idx = blockIdx.x * 256 + threadIdx.x;
    if (idx < N_NODES) {
        int p = ptr[idx] + bsum[blockIdx.x];
        ptr[idx] = p;
        fill[idx] = p;
    }
    if (idx == 0) ptr[N_NODES] = N_EDGES;
}

// scatter: slotmap[pos] = {edge id, dst node}
__global__ __launch_bounds__(256) void scatter_kernel(const int* __restrict__ eidx,
                                                      int* __restrict__ fill,
                                                      int2* __restrict__ slotmap) {
    int e = blockIdx.x * blockDim.x + threadIdx.x;
    if (e >= N_EDGES) return;
    int dst = eidx[(size_t)N_EDGES + e];
    int pos = atomicAdd(&fill[dst], 1);
    slotmap[pos] = make_int2(e, dst);
}

// ---------------- slot-parallel segment sum ----------------
// 32-lane group handles SPG consecutive sorted slots; lane c owns channel c.
// out must be pre-zeroed (atomic boundary adds + zero-degree nodes).
__global__ __launch_bounds__(256) void seg_sum_kernel(const float* __restrict__ V,
                                                      const int2* __restrict__ slotmap,
                                                      const int* __restrict__ ptr,
                                                      float* __restrict__ out) {
    int g = (blockIdx.x * blockDim.x + threadIdx.x) >> 5;   // global group id
    int lane = threadIdx.x & 31;
    int gstart = g * SPG;

    float acc = 0.0f;
    int cur = slotmap[gstart].y;   // same address all lanes -> broadcast

    for (int k = 0; k < SPG / 32; ++k) {
        int2 sm = slotmap[gstart + k * 32 + lane];          // coalesced 8B
#pragma unroll
        for (int j = 0; j < 32; ++j) {
            int e = __shfl(sm.x, j, 32);
            int n = __shfl(sm.y, j, 32);
            float v = V[(size_t)e * H + lane];              // coalesced 128B row
            if (n != cur) {
                int b = ptr[cur], en = ptr[cur + 1];
                if (b >= gstart && en <= gstart + SPG)
                    out[(size_t)cur * H + lane] = acc;      // segment fully ours
                else
                    atomicAdd(out + (size_t)cur * H + lane, acc);
                cur = n;
                acc = v;
            } else {
                acc += v;
            }
        }
    }
    int b = ptr[cur], en = ptr[cur + 1];
    if (b >= gstart && en <= gstart + SPG)
        out[(size_t)cur * H + lane] = acc;
    else
        atomicAdd(out + (size_t)cur * H + lane, acc);
}

// ---------------- per-node: pre1 transform + N_node MLP -> pernode[n][64] ----------------
__global__ __launch_bounds__(256) void pernode_kernel(const float* __restrict__ x,
                                                      const float* __restrict__ raw,
                                                      const int* __restrict__ ptr,
                                                      const float* __restrict__ W_in,
                                                      const float* __restrict__ b_in,
                                                      const float* __restrict__ Wn1,
                                                      const float* __restrict__ bn1,
                                                      const float* __restrict__ Wn2,
                                                      const float* __restrict__ bn2,
                                                      const float* __restrict__ W2,
                                                      const float* __restrict__ c1,
                                                      const float* __restrict__ c0,
                                                      float* __restrict__ pernode) {
    int i = blockIdx.x * blockDim.x + threadIdx.x;
    if (i >= N_NODES) return;
    float s[H], p1[H];
    // pre1 = raw @ W2 + deg*c1 + c0
    load_row32(raw + (size_t)i * H, s);
    float deg = (float)(ptr[i + 1] - ptr[i]);
#pragma unroll
    for (int o = 0; o < H; ++o) p1[o] = fmaf(deg, c1[o], c0[o]);
    matvec32_acc(s, W2, p1);
    store_row32(pernode + (size_t)i * 64, p1);
    // nn = lrelu(lrelu(h_node@Wn1+bn1)@Wn2+bn2)
    hnode_row(x, i, W_in, b_in, s);
    matvec32(s, Wn1, bn1, p1);
#pragma unroll
    for (int o = 0; o < H; ++o) p1[o] = lrelu(p1[o]);
    matvec32(p1, Wn2, bn2, s);
#pragma unroll
    for (int o = 0; o < H; ++o) s[o] = lrelu(s[o]);
    store_row32(pernode + (size_t)i * 64 + 32, s);
}

// ---------------- pass2: per-edge, folded ----------------
__global__ __launch_bounds__(256) void edge_pass2_kernel(
    const float* __restrict__ h_msg, const int* __restrict__ eidx,
    const float* __restrict__ pernode,
    const float* __restrict__ Wfold,
    const float* __restrict__ WN2, const float* __restrict__ bN2,
    const float* __restrict__ Wd, const float* __restrict__ bd,
    float* __restrict__ out_hmsg, float* __restrict__ out_ymsg) {
    int e = blockIdx.x * blockDim.x + threadIdx.x;   // grid exact (3.2M/256)
    int src = eidx[e];

    float m[H], t[H], u[H];

    // t = pre1[src] + h_msg[e] @ Wfold     (== cat_e @ WN1 + bN1)
    load_row32(h_msg + (size_t)e * H, m);
    load_row32(pernode + (size_t)src * 64, t);
    matvec32_acc(m, Wfold, t);
#pragma unroll
    for (int o = 0; o < H; ++o) t[o] = lrelu(t[o]);

    // u = t @ WN2 + bN2
    matvec32(t, WN2, bN2, u);

    // h_msg_new = nn_node[src] + lrelu(u)
    load_row32(pernode + (size_t)src * 64 + 32, t);
#pragma unroll
    for (int o = 0; o < H; ++o) m[o] = t[o] + lrelu(u[o]);

    store_row32(out_hmsg + (size_t)e * H, m);

    // y_msg = softmax(h_msg_new @ Wd + bd)
    float z0 = bd[0], z1 = bd[1];
#pragma unroll
    for (int k = 0; k < H; ++k) {
        z0 = fmaf(m[k], Wd[k * 2 + 0], z0);
        z1 = fmaf(m[k], Wd[k * 2 + 1], z1);
    }
    float zm = fmaxf(z0, z1);
    float e0 = __expf(z0 - zm), e1 = __expf(z1 - zm);
    float inv = 1.0f / (e0 + e1);
    out_ymsg[(size_t)e * 2 + 0] = e0 * inv;
    out_ymsg[(size_t)e * 2 + 1] = e1 * inv;
}

// ---------------- node update + beliefs ----------------
__global__ __launch_bounds__(256) void node_update_kernel(
    const float* __restrict__ x, const float* __restrict__ aggr_out,
    const float* __restrict__ W_in, const float* __restrict__ b_in,
    const float* __restrict__ WU, const float* __restrict__ bU,
    const float* __restrict__ Wb, const float* __restrict__ bb,
    float* __restrict__ out_beliefs) {
    int i = blockIdx.x * blockDim.x + threadIdx.x;
    if (i >= N_NODES) return;
    float a[H], t[H];
    hnode_row(x, i, W_in, b_in, a);
    matvec32(a, WU, bU, t);
    load_row32(aggr_out + (size_t)i * H, a);
    matvec32_acc(a, WU + H * H, t);
#pragma unroll
    for (int o = 0; o < H; ++o) t[o] = lrelu(t[o]);

    // beliefs only for variable nodes (x[:,0]==1, contiguous prefix -> out row == i)
    if (x[(size_t)i * 3] == 1.0f) {
        float z0 = bb[0], z1 = bb[1];
#pragma unroll
        for (int k = 0; k < H; ++k) {
            z0 = fmaf(t[k], Wb[k * 2 + 0], z0);
            z1 = fmaf(t[k], Wb[k * 2 + 1], z1);
        }
        float zm = fmaxf(z0, z1);
        float e0 = __expf(z0 - zm), e1 = __expf(z1 - zm);
        float inv = 1.0f / (e0 + e1);
        out_beliefs[(size_t)i * 2 + 0] = e0 * inv;
        out_beliefs[(size_t)i * 2 + 1] = e1 * inv;
    }
}

extern "C" void kernel_launch(void* const* d_in, const int* in_sizes, int n_in,
                              void* d_out, int out_size, void* d_ws, size_t ws_size,
                              hipStream_t stream) {
    const float* x     = (const float*)d_in[0];
    const int*   eidx  = (const int*)d_in[1];
    const float* h_msg = (const float*)d_in[2];
    const float* W_in = (const float*)d_in[3];  const float* b_in = (const float*)d_in[4];
    const float* We   = (const float*)d_in[5];  const float* be   = (const float*)d_in[6];
    const float* Wn1  = (const float*)d_in[7];  const float* bn1  = (const float*)d_in[8];
    const float* Wn2  = (const float*)d_in[9];  const float* bn2  = (const float*)d_in[10];
    const float* WN1  = (const float*)d_in[11]; const float* bN1  = (const float*)d_in[12];
    const float* WN2  = (const float*)d_in[13]; const float* bN2  = (const float*)d_in[14];
    const float* WU   = (const float*)d_in[15]; const float* bU   = (const float*)d_in[16];
    const float* Wd   = (const float*)d_in[17]; const float* bd   = (const float*)d_in[18];
    const float* Wb   = (const float*)d_in[19]; const float* bb   = (const float*)d_in[20];

    float* out         = (float*)d_out;
    float* out_hmsg    = out;
    float* out_ymsg    = out + (size_t)N_EDGES * H;
    float* out_beliefs = out + (size_t)N_EDGES * (H + 2);

    // workspace layout (~65 MB)
    float* pernode = (float*)d_ws;                              // [N, 64] pre1|nn
    float* raw     = pernode + (size_t)N_NODES * 64;            // [N, H] h_msg sums, then aggr_out
    int2*  slotmap = (int2*)(raw + (size_t)N_NODES * H);        // [E] {edge, dst}
    float* W2      = (float*)(slotmap + N_EDGES);               // [H*H]
    float* Wfold   = W2 + H * H;                                // [H*H]
    float* c1      = Wfold + H * H;                             // [H]
    float* c0      = c1 + H;                                    // [H]
    int*   cnt     = (int*)(c0 + H);                            // [N]
    int*   ptr     = cnt + N_NODES;                             // [N+1]
    int*   fill    = ptr + (N_NODES + 1);                       // [N]
    int*   bsum    = fill + N_NODES;                            // [512]

    const int EB    = N_EDGES / 256;              // 12500 exact
    const int SEGB  = N_EDGES / (SPG * 8);        // 3125 blocks (8 groups/block) exact
    const int RAW4  = (N_NODES * H) / 4;          // float4 count for raw

    // --- folded weight matrices ---
    fold_kernel<<<1, 1024, 0, stream>>>(We, be, WN1, bN1, W2, Wfold, c1, c0);

    // --- CSR build (by dst) ---
    zero_int_kernel<<<SCAN_BLOCKS, 256, 0, stream>>>(cnt, N_NODES);
    hist_kernel<<<EB, 256, 0, stream>>>(eidx, cnt);
    scan_block_kernel<<<SCAN_BLOCKS, 256, 0, stream>>>(cnt, ptr, bsum);
    scan_bsum_kernel<<<1, 512, 0, stream>>>(bsum, SCAN_BLOCKS);
    scan_fix_kernel<<<SCAN_BLOCKS, 256, 0, stream>>>(ptr, fill, bsum);
    scatter_kernel<<<EB, 256, 0, stream>>>(eidx, fill, slotmap);

    // --- raw = segment_sum(h_msg, dst) ---
    zero_f4_kernel<<<(RAW4 + 255) / 256, 256, 0, stream>>>((float4*)raw, RAW4);
    seg_sum_kernel<<<SEGB, 256, 0, stream>>>(h_msg, slotmap, ptr, raw);

    // --- pernode: pre1 transform + nn_node ---
    pernode_kernel<<<SCAN_BLOCKS, 256, 0, stream>>>(
        x, raw, ptr, W_in, b_in, Wn1, bn1, Wn2, bn2, W2, c1, c0, pernode);

    // --- per-edge messages ---
    edge_pass2_kernel<<<EB, 256, 0, stream>>>(
        h_msg, eidx, pernode, Wfold, WN2, bN2, Wd, bd, out_hmsg, out_ymsg);

    // --- raw = segment_sum(h_msg_new, dst)  (reuse raw slot) ---
    zero_f4_kernel<<<(RAW4 + 255) / 256, 256, 0, stream>>>((float4*)raw, RAW4);
    seg_sum_kernel<<<SEGB, 256, 0, stream>>>(out_hmsg, slotmap, ptr, raw);

    // --- node update + beliefs ---
    node_update_kernel<<<SCAN_BLOCKS, 256, 0, stream>>>(
        x, raw, W_in, b_in, WU, bU, Wb, bb, out_beliefs);
}

// Round 7
// 1132.819 us; speedup vs baseline: 1.6813x; 1.1088x over previous
//
#include <hip/hip_runtime.h>
#include <math.h>

#define N_NODES 100000
#define N_EDGES 3200000
#define H 32
#define SCAN_BLOCKS ((N_NODES + 255) / 256)   // 391
#define LDS_STRIDE 33                         // conflict-free: bank = (row+lane)%32

__device__ __forceinline__ float lrelu(float v) { return v > 0.0f ? v : 0.01f * v; }

// out = bias + in @ W   (W is [H,H] row-major: W[k*H+o]); uniform W/bias -> s_loads
__device__ __forceinline__ void matvec32(const float* __restrict__ in,
                                         const float* __restrict__ W,
                                         const float* __restrict__ bias,
                                         float* __restrict__ out) {
#pragma unroll
    for (int o = 0; o < H; ++o) out[o] = bias[o];
#pragma unroll
    for (int k = 0; k < H; ++k) {
        float v = in[k];
#pragma unroll
        for (int o = 0; o < H; ++o) out[o] = fmaf(v, W[k * H + o], out[o]);
    }
}

// out += in @ W
__device__ __forceinline__ void matvec32_acc(const float* __restrict__ in,
                                             const float* __restrict__ W,
                                             float* __restrict__ out) {
#pragma unroll
    for (int k = 0; k < H; ++k) {
        float v = in[k];
#pragma unroll
        for (int o = 0; o < H; ++o) out[o] = fmaf(v, W[k * H + o], out[o]);
    }
}

__device__ __forceinline__ void load_row32(const float* __restrict__ p, float* __restrict__ r) {
    const float4* p4 = reinterpret_cast<const float4*>(p);
#pragma unroll
    for (int q = 0; q < 8; ++q) {
        float4 v = p4[q];
        r[4 * q + 0] = v.x; r[4 * q + 1] = v.y; r[4 * q + 2] = v.z; r[4 * q + 3] = v.w;
    }
}

__device__ __forceinline__ void store_row32(float* __restrict__ p, const float* __restrict__ r) {
    float4* p4 = reinterpret_cast<float4*>(p);
#pragma unroll
    for (int q = 0; q < 8; ++q) {
        float4 v;
        v.x = r[4 * q + 0]; v.y = r[4 * q + 1]; v.z = r[4 * q + 2]; v.w = r[4 * q + 3];
        p4[q] = v;
    }
}

// h_node row for node i from x[i] (W_in is [3,H])
__device__ __forceinline__ void hnode_row(const float* __restrict__ x, int i,
                                          const float* __restrict__ W_in,
                                          const float* __restrict__ b_in,
                                          float* __restrict__ r) {
    float x0 = x[(size_t)i * 3 + 0], x1 = x[(size_t)i * 3 + 1], x2 = x[(size_t)i * 3 + 2];
#pragma unroll
    for (int o = 0; o < H; ++o)
        r[o] = fmaf(x2, W_in[2 * H + o], fmaf(x1, W_in[1 * H + o], fmaf(x0, W_in[0 * H + o], b_in[o])));
}

// per-group segment scan over 32 staged LDS slots; lane owns one channel.
// Interior segments (start AND end observed) -> plain store (exclusively ours);
// first/last segments of the group -> atomicAdd into pre-zeroed table.
__device__ __forceinline__ void seg_scan32(const float* __restrict__ tile,
                                           const int* __restrict__ nid,
                                           int base, int lane,
                                           float* __restrict__ out) {
    int cur = nid[base];
    float acc = tile[base * LDS_STRIDE + lane];
    bool started = false;
#pragma unroll 4
    for (int j = 1; j < 32; ++j) {
        int n = nid[base + j];
        float v = tile[(base + j) * LDS_STRIDE + lane];
        if (n != cur) {
            if (started) out[(size_t)cur * H + lane] = acc;
            else atomicAdd(out + (size_t)cur * H + lane, acc);
            started = true;
            cur = n;
            acc = v;
        } else {
            acc += v;
        }
    }
    atomicAdd(out + (size_t)cur * H + lane, acc);   // last segment: end unknown
}

// ---------------- fold: W2 = We@WN1top, Wfold = We@WN1bot, c1 = be@WN1top,
//                  c0 = bN1 + be@WN1bot ----------------
__global__ __launch_bounds__(1024) void fold_kernel(const float* __restrict__ We,
                                                    const float* __restrict__ be,
                                                    const float* __restrict__ WN1,
                                                    const float* __restrict__ bN1,
                                                    float* __restrict__ W2,
                                                    float* __restrict__ Wfold,
                                                    float* __restrict__ c1,
                                                    float* __restrict__ c0) {
    int t = threadIdx.x;
    int k = t >> 5, o = t & 31;
    float s2 = 0.0f, sf = 0.0f;
#pragma unroll
    for (int j = 0; j < H; ++j) {
        float w = We[k * H + j];
        s2 = fmaf(w, WN1[j * H + o], s2);
        sf = fmaf(w, WN1[(H + j) * H + o], sf);
    }
    W2[t] = s2;
    Wfold[t] = sf;
    if (k == 0) {
        float a = 0.0f, b = 0.0f;
#pragma unroll
        for (int j = 0; j < H; ++j) {
            a = fmaf(be[j], WN1[j * H + o], a);
            b = fmaf(be[j], WN1[(H + j) * H + o], b);
        }
        c1[o] = a;
        c0[o] = bN1[o] + b;
    }
}

// ---------------- utility zero kernels ----------------
__global__ __launch_bounds__(256) void zero_int_kernel(int* __restrict__ p, int n) {
    int i = blockIdx.x * blockDim.x + threadIdx.x;
    if (i < n) p[i] = 0;
}

__global__ __launch_bounds__(256) void zero_f4_kernel(float4* __restrict__ p, int n4) {
    int i = blockIdx.x * blockDim.x + threadIdx.x;
    if (i < n4) p[i] = make_float4(0.f, 0.f, 0.f, 0.f);
}

// ---------------- CSR build ----------------
__global__ __launch_bounds__(256) void hist_kernel(const int* __restrict__ eidx, int* __restrict__ cnt) {
    int e = blockIdx.x * blockDim.x + threadIdx.x;
    if (e >= N_EDGES) return;
    atomicAdd(&cnt[eidx[(size_t)N_EDGES + e]], 1);
}

__global__ __launch_bounds__(256) void scan_block_kernel(const int* __restrict__ cnt,
                                                         int* __restrict__ ptr,
                                                         int* __restrict__ bsum) {
    __shared__ int sm[256];
    int idx = blockIdx.x * 256 + threadIdx.x;
    int v = (idx < N_NODES) ? cnt[idx] : 0;
    sm[threadIdx.x] = v;
    __syncthreads();
    for (int off = 1; off < 256; off <<= 1) {
        int t = (threadIdx.x >= off) ? sm[threadIdx.x - off] : 0;
        __syncthreads();
        sm[threadIdx.x] += t;
        __syncthreads();
    }
    if (idx < N_NODES) ptr[idx] = sm[threadIdx.x] - v;   // exclusive within block
    if (threadIdx.x == 255) bsum[blockIdx.x] = sm[255];
}

__global__ __launch_bounds__(512) void scan_bsum_kernel(int* __restrict__ bsum, int nb) {
    __shared__ int sm[512];
    int v = (threadIdx.x < nb) ? bsum[threadIdx.x] : 0;
    sm[threadIdx.x] = v;
    __syncthreads();
    for (int off = 1; off < 512; off <<= 1) {
        int t = (threadIdx.x >= off) ? sm[threadIdx.x - off] : 0;
        __syncthreads();
        sm[threadIdx.x] += t;
        __syncthreads();
    }
    if (threadIdx.x < nb) bsum[threadIdx.x] = sm[threadIdx.x] - v;  // exclusive
}

__global__ __launch_bounds__(256) void scan_fix_kernel(int* __restrict__ ptr,
                                                       int* __restrict__ fill,
                                                       const int* __restrict__ bsum) {
    int idx = blockIdx.x * 256 + threadIdx.x;
    if (idx < N_NODES) {
        int p = ptr[idx] + bsum[blockIdx.x];
        ptr[idx] = p;
        fill[idx] = p;
    }
    if (idx == 0) ptr[N_NODES] = N_EDGES;
}

// scatter: slotmap[pos] = {edge id, dst node}
__global__ __launch_bounds__(256) void scatter_kernel(const int* __restrict__ eidx,
                                                      int* __restrict__ fill,
                                                      int2* __restrict__ slotmap) {
    int e = blockIdx.x * blockDim.x + threadIdx.x;
    if (e >= N_EDGES) return;
    int dst = eidx[(size_t)N_EDGES + e];
    int pos = atomicAdd(&fill[dst], 1);
    slotmap[pos] = make_int2(e, dst);
}

// ---------------- seg_sum1: LDS-staged segment sum of h_msg rows ----------------
__global__ __launch_bounds__(256) void seg_stage_kernel(const float* __restrict__ V,
                                                        const int2* __restrict__ slotmap,
                                                        float* __restrict__ out) {
    __shared__ float tile[256 * LDS_STRIDE];
    __shared__ int nid[256];
    int tid = threadIdx.x;
    int slot = blockIdx.x * 256 + tid;
    int2 sm = slotmap[slot];
    float m[H];
    load_row32(V + (size_t)sm.x * H, m);     // 8 independent b128 loads -> pipelined
    nid[tid] = sm.y;
#pragma unroll
    for (int o = 0; o < H; ++o) tile[tid * LDS_STRIDE + o] = m[o];
    __syncthreads();
    seg_scan32(tile, nid, tid & ~31, tid & 31, out);
}

// ---------------- per-node: pre1 transform + N_node MLP -> pernode[n][64] ----------------
__global__ __launch_bounds__(256) void pernode_kernel(const float* __restrict__ x,
                                                      const float* __restrict__ raw,
                                                      const int* __restrict__ ptr,
                                                      const float* __restrict__ W_in,
                                                      const float* __restrict__ b_in,
                                                      const float* __restrict__ Wn1,
                                                      const float* __restrict__ bn1,
                                                      const float* __restrict__ Wn2,
                                                      const float* __restrict__ bn2,
                                                      const float* __restrict__ W2,
                                                      const float* __restrict__ c1,
                                                      const float* __restrict__ c0,
                                                      float* __restrict__ pernode) {
    int i = blockIdx.x * blockDim.x + threadIdx.x;
    if (i >= N_NODES) return;
    float s[H], p1[H];
    // pre1 = raw @ W2 + deg*c1 + c0
    load_row32(raw + (size_t)i * H, s);
    float deg = (float)(ptr[i + 1] - ptr[i]);
#pragma unroll
    for (int o = 0; o < H; ++o) p1[o] = fmaf(deg, c1[o], c0[o]);
    matvec32_acc(s, W2, p1);
    store_row32(pernode + (size_t)i * 64, p1);
    // nn = lrelu(lrelu(h_node@Wn1+bn1)@Wn2+bn2)
    hnode_row(x, i, W_in, b_in, s);
    matvec32(s, Wn1, bn1, p1);
#pragma unroll
    for (int o = 0; o < H; ++o) p1[o] = lrelu(p1[o]);
    matvec32(p1, Wn2, bn2, s);
#pragma unroll
    for (int o = 0; o < H; ++o) s[o] = lrelu(s[o]);
    store_row32(pernode + (size_t)i * 64 + 32, s);
}

// ---------------- fused pass2: per-edge MLP (slot order) + inline aggr_out ----------------
__global__ __launch_bounds__(256) void edge_fused_kernel(
    const float* __restrict__ h_msg, const int* __restrict__ eidx,
    const int2* __restrict__ slotmap,
    const float* __restrict__ pernode,
    const float* __restrict__ Wfold,
    const float* __restrict__ WN2, const float* __restrict__ bN2,
    const float* __restrict__ Wd, const float* __restrict__ bd,
    float* __restrict__ out_hmsg, float* __restrict__ out_ymsg,
    float* __restrict__ aggr_out) {
    __shared__ float tile[256 * LDS_STRIDE];
    __shared__ int nid[256];
    int tid = threadIdx.x;
    int slot = blockIdx.x * 256 + tid;      // grid exact (3.2M/256)
    int2 sm = slotmap[slot];
    int e = sm.x;
    int src = eidx[e];                       // src gather (12.8MB table, cache-resident)

    float m[H], t[H], u[H];

    // t = pre1[src] + h_msg[e] @ Wfold     (== cat_e @ WN1 + bN1)
    load_row32(h_msg + (size_t)e * H, m);
    load_row32(pernode + (size_t)src * 64, t);
    matvec32_acc(m, Wfold, t);
#pragma unroll
    for (int o = 0; o < H; ++o) t[o] = lrelu(t[o]);

    // u = t @ WN2 + bN2
    matvec32(t, WN2, bN2, u);

    // h_msg_new = nn_node[src] + lrelu(u)
    load_row32(pernode + (size_t)src * 64 + 32, t);
#pragma unroll
    for (int o = 0; o < H; ++o) m[o] = t[o] + lrelu(u[o]);

    store_row32(out_hmsg + (size_t)e * H, m);

    // y_msg = softmax(h_msg_new @ Wd + bd)
    float z0 = bd[0], z1 = bd[1];
#pragma unroll
    for (int k = 0; k < H; ++k) {
        z0 = fmaf(m[k], Wd[k * 2 + 0], z0);
        z1 = fmaf(m[k], Wd[k * 2 + 1], z1);
    }
    float zm = fmaxf(z0, z1);
    float e0 = __expf(z0 - zm), e1 = __expf(z1 - zm);
    float inv = 1.0f / (e0 + e1);
    *reinterpret_cast<float2*>(out_ymsg + (size_t)e * 2) = make_float2(e0 * inv, e1 * inv);

    // stage h_msg_new into LDS and segment-sum into aggr_out (replaces seg_sum2)
    nid[tid] = sm.y;
#pragma unroll
    for (int o = 0; o < H; ++o) tile[tid * LDS_STRIDE + o] = m[o];
    __syncthreads();
    seg_scan32(tile, nid, tid & ~31, tid & 31, aggr_out);
}

// ---------------- node update + beliefs ----------------
__global__ __launch_bounds__(256) void node_update_kernel(
    const float* __restrict__ x, const float* __restrict__ aggr_out,
    const float* __restrict__ W_in, const float* __restrict__ b_in,
    const float* __restrict__ WU, const float* __restrict__ bU,
    const float* __restrict__ Wb, const float* __restrict__ bb,
    float* __restrict__ out_beliefs) {
    int i = blockIdx.x * blockDim.x + threadIdx.x;
    if (i >= N_NODES) return;
    float a[H], t[H];
    hnode_row(x, i, W_in, b_in, a);
    matvec32(a, WU, bU, t);
    load_row32(aggr_out + (size_t)i * H, a);
    matvec32_acc(a, WU + H * H, t);
#pragma unroll
    for (int o = 0; o < H; ++o) t[o] = lrelu(t[o]);

    // beliefs only for variable nodes (x[:,0]==1, contiguous prefix -> out row == i)
    if (x[(size_t)i * 3] == 1.0f) {
        float z0 = bb[0], z1 = bb[1];
#pragma unroll
        for (int k = 0; k < H; ++k) {
            z0 = fmaf(t[k], Wb[k * 2 + 0], z0);
            z1 = fmaf(t[k], Wb[k * 2 + 1], z1);
        }
        float zm = fmaxf(z0, z1);
        float e0 = __expf(z0 - zm), e1 = __expf(z1 - zm);
        float inv = 1.0f / (e0 + e1);
        out_beliefs[(size_t)i * 2 + 0] = e0 * inv;
        out_beliefs[(size_t)i * 2 + 1] = e1 * inv;
    }
}

extern "C" void kernel_launch(void* const* d_in, const int* in_sizes, int n_in,
                              void* d_out, int out_size, void* d_ws, size_t ws_size,
                              hipStream_t stream) {
    const float* x     = (const float*)d_in[0];
    const int*   eidx  = (const int*)d_in[1];
    const float* h_msg = (const float*)d_in[2];
    const float* W_in = (const float*)d_in[3];  const float* b_in = (const float*)d_in[4];
    const float* We   = (const float*)d_in[5];  const float* be   = (const float*)d_in[6];
    const float* Wn1  = (const float*)d_in[7];  const float* bn1  = (const float*)d_in[8];
    const float* Wn2  = (const float*)d_in[9];  const float* bn2  = (const float*)d_in[10];
    const float* WN1  = (const float*)d_in[11]; const float* bN1  = (const float*)d_in[12];
    const float* WN2  = (const float*)d_in[13]; const float* bN2  = (const float*)d_in[14];
    const float* WU   = (const float*)d_in[15]; const float* bU   = (const float*)d_in[16];
    const float* Wd   = (const float*)d_in[17]; const float* bd   = (const float*)d_in[18];
    const float* Wb   = (const float*)d_in[19]; const float* bb   = (const float*)d_in[20];

    float* out         = (float*)d_out;
    float* out_hmsg    = out;
    float* out_ymsg    = out + (size_t)N_EDGES * H;
    float* out_beliefs = out + (size_t)N_EDGES * (H + 2);

    // workspace layout (~65 MB)
    float* pernode = (float*)d_ws;                              // [N, 64] pre1|nn
    float* raw     = pernode + (size_t)N_NODES * 64;            // [N, H] h_msg sums, then aggr_out
    int2*  slotmap = (int2*)(raw + (size_t)N_NODES * H);        // [E] {edge, dst}
    float* W2      = (float*)(slotmap + N_EDGES);               // [H*H]
    float* Wfold   = W2 + H * H;                                // [H*H]
    float* c1      = Wfold + H * H;                             // [H]
    float* c0      = c1 + H;                                    // [H]
    int*   cnt     = (int*)(c0 + H);                            // [N]
    int*   ptr     = cnt + N_NODES;                             // [N+1]
    int*   fill    = ptr + (N_NODES + 1);                       // [N]
    int*   bsum    = fill + N_NODES;                            // [512]

    const int EB   = N_EDGES / 256;               // 12500 exact
    const int RAW4 = (N_NODES * H) / 4;           // float4 count for raw

    // --- folded weight matrices ---
    fold_kernel<<<1, 1024, 0, stream>>>(We, be, WN1, bN1, W2, Wfold, c1, c0);

    // --- CSR build (by dst) ---
    zero_int_kernel<<<SCAN_BLOCKS, 256, 0, stream>>>(cnt, N_NODES);
    hist_kernel<<<EB, 256, 0, stream>>>(eidx, cnt);
    scan_block_kernel<<<SCAN_BLOCKS, 256, 0, stream>>>(cnt, ptr, bsum);
    scan_bsum_kernel<<<1, 512, 0, stream>>>(bsum, SCAN_BLOCKS);
    scan_fix_kernel<<<SCAN_BLOCKS, 256, 0, stream>>>(ptr, fill, bsum);
    scatter_kernel<<<EB, 256, 0, stream>>>(eidx, fill, slotmap);

    // --- raw = segment_sum(h_msg, dst) ---
    zero_f4_kernel<<<(RAW4 + 255) / 256, 256, 0, stream>>>((float4*)raw, RAW4);
    seg_stage_kernel<<<EB, 256, 0, stream>>>(h_msg, slotmap, raw);

    // --- pernode: pre1 transform + nn_node ---
    pernode_kernel<<<SCAN_BLOCKS, 256, 0, stream>>>(
        x, raw, ptr, W_in, b_in, Wn1, bn1, Wn2, bn2, W2, c1, c0, pernode);

    // --- re-zero raw for aggr_out accumulation ---
    zero_f4_kernel<<<(RAW4 + 255) / 256, 256, 0, stream>>>((float4*)raw, RAW4);

    // --- fused: per-edge messages + inline segment_sum(h_msg_new) ---
    edge_fused_kernel<<<EB, 256, 0, stream>>>(
        h_msg, eidx, slotmap, pernode, Wfold, WN2, bN2, Wd, bd,
        out_hmsg, out_ymsg, raw);

    // --- node update + beliefs ---
    node_update_kernel<<<SCAN_BLOCKS, 256, 0, stream>>>(
        x, raw, W_in, b_in, WU, bU, Wb, bb, out_beliefs);
}